// Round 3
// baseline (219.729 us; speedup 1.0000x reference)
//
#include <hip/hip_runtime.h>

#define N_NODES 100000
#define DEG 16
#define E_EDGES (N_NODES * DEG)
#define D_DIM 128
#define U_DIM 128
#define M_TILE 128
#define N_SLICES 8          // 16 cols per slice; one slice = 3.2 MB bf16, fits a 4 MB XCD L2
#define NODES_PER_BLOCK 128

typedef __bf16 bf16x8 __attribute__((ext_vector_type(8)));
typedef float f32x4 __attribute__((ext_vector_type(4)));

__device__ __forceinline__ unsigned short f2bf(float x) {
    // round-to-nearest-even fp32 -> bf16 (inputs finite)
    unsigned int u = __float_as_uint(x);
    u += 0x7fffu + ((u >> 16) & 1u);
    return (unsigned short)(u >> 16);
}

// W fp32 [K=128][U=128] row-major -> WT bf16 [U][K] (B-fragment friendly: k contiguous)
__global__ void cast_w_kernel(const float* __restrict__ W,
                              unsigned short* __restrict__ WT) {
    int t = blockIdx.x * 256 + threadIdx.x;   // t < 16384
    int k = t >> 7, n = t & 127;
    WT[n * 128 + k] = f2bf(W[t]);
}

// Y = feat @ W (bf16 MFMA, fp32 acc), stored SLICE-MAJOR:
//   Ys[s][row][c] bf16, s = col/16, c = col%16  ->  slice s is contiguous 3.2 MB
__global__ __launch_bounds__(256)
void ymat_kernel(const float* __restrict__ feat,
                 const unsigned short* __restrict__ WT,   // bf16 [U][K]
                 unsigned short* __restrict__ Ys) {
    const int lane = threadIdx.x & 63;
    const int wv = threadIdx.x >> 6;
    const int block0 = blockIdx.x * M_TILE;
    const int quad = lane >> 4;
    const int l15 = lane & 15;

    f32x4 acc[2][8];
    #pragma unroll
    for (int mi = 0; mi < 2; ++mi)
        #pragma unroll
        for (int ni = 0; ni < 8; ++ni)
            acc[mi][ni] = (f32x4){0.f, 0.f, 0.f, 0.f};

    #pragma unroll
    for (int kc = 0; kc < 4; ++kc) {
        bf16x8 bfr[8];
        #pragma unroll
        for (int ni = 0; ni < 8; ++ni)   // B[k][n]: n = l15+16ni, k = kc*32+quad*8+j
            bfr[ni] = *(const bf16x8*)(WT + (ni * 16 + l15) * 128 + kc * 32 + quad * 8);
        bf16x8 afr[2];
        #pragma unroll
        for (int mi = 0; mi < 2; ++mi) {
            int row = block0 + wv * 32 + mi * 16 + l15;
            if (row >= N_NODES) row = N_NODES - 1;       // clamp; store is guarded
            const float* ap = feat + (size_t)row * D_DIM + kc * 32 + quad * 8;
            const float4 a0 = *(const float4*)ap;
            const float4 a1 = *(const float4*)(ap + 4);
            union { unsigned short us[8]; bf16x8 b; } pk;
            pk.us[0] = f2bf(a0.x); pk.us[1] = f2bf(a0.y);
            pk.us[2] = f2bf(a0.z); pk.us[3] = f2bf(a0.w);
            pk.us[4] = f2bf(a1.x); pk.us[5] = f2bf(a1.y);
            pk.us[6] = f2bf(a1.z); pk.us[7] = f2bf(a1.w);
            afr[mi] = pk.b;
        }
        #pragma unroll
        for (int mi = 0; mi < 2; ++mi)
            #pragma unroll
            for (int ni = 0; ni < 8; ++ni)
                acc[mi][ni] = __builtin_amdgcn_mfma_f32_16x16x32_bf16(afr[mi], bfr[ni], acc[mi][ni], 0, 0, 0);
    }

    // D[row][col]: row = quad*4+r, col = ni*16+l15 -> slice ni, within-slice offset l15
    #pragma unroll
    for (int mi = 0; mi < 2; ++mi)
        #pragma unroll
        for (int r = 0; r < 4; ++r) {
            const int row = block0 + wv * 32 + mi * 16 + quad * 4 + r;
            if (row < N_NODES) {
                #pragma unroll
                for (int ni = 0; ni < 8; ++ni)
                    Ys[(size_t)ni * (N_NODES * 16) + (size_t)row * 16 + l15] =
                        f2bf(acc[mi][ni][r]);
            }
        }
}

// out[n, 16s:16s+16] = relu( (sum_e w_e * Ys[s][col_e]) / (sum_e w_e) + b[16s:16s+16] )
// slice = blockIdx % 8  -> with round-robin block->XCD dispatch, XCD s only touches
// slice s (3.2 MB, L2-resident). 8 threads per node; thread j owns dims {2j, 2j+1}.
__global__ __launch_bounds__(256, 6)
void agg_kernel(const unsigned int* __restrict__ Ys_u32,  // bf16 pairs [8][N][8] dwords
                const int* __restrict__ cols,
                const float* __restrict__ wts,
                const float* __restrict__ bias,
                float* __restrict__ out) {
    const int slice = blockIdx.x & (N_SLICES - 1);
    const int nb = blockIdx.x >> 3;                    // 0..781
    const int n0 = nb * NODES_PER_BLOCK;
    const int j = threadIdx.x & 7;
    const int nl = threadIdx.x >> 3;                   // 0..31

    const float2 bv = ((const float2*)bias)[slice * 8 + j];
    const unsigned int* Sbase = Ys_u32 + (size_t)slice * N_NODES * 8;

    #pragma unroll
    for (int it = 0; it < 4; ++it) {
        const int node = n0 + it * 32 + nl;
        if (node >= N_NODES) continue;                 // only last block/slice diverges

        // edge data: 8 threads of a node read the same lines -> L1 broadcast
        const int4* cp = (const int4*)(cols + node * DEG);
        const float4* wp = (const float4*)(wts + node * DEG);
        int cc[DEG];
        float ww[DEG];
        #pragma unroll
        for (int q = 0; q < 4; ++q) {
            const int4 c4 = cp[q];
            const float4 w4 = wp[q];
            cc[q * 4 + 0] = c4.x; cc[q * 4 + 1] = c4.y;
            cc[q * 4 + 2] = c4.z; cc[q * 4 + 3] = c4.w;
            ww[q * 4 + 0] = w4.x; ww[q * 4 + 1] = w4.y;
            ww[q * 4 + 2] = w4.z; ww[q * 4 + 3] = w4.w;
        }

        // issue all 16 gathers (L2-hit after warmup), then consume
        unsigned int p[DEG];
        #pragma unroll
        for (int e = 0; e < DEG; ++e)
            p[e] = Sbase[(size_t)cc[e] * 8 + j];

        float ax = 0.f, ay = 0.f, den = 0.f;
        #pragma unroll
        for (int e = 0; e < DEG; ++e) {
            const float fx = __uint_as_float(p[e] << 16);
            const float fy = __uint_as_float(p[e] & 0xffff0000u);
            ax = fmaf(ww[e], fx, ax);
            ay = fmaf(ww[e], fy, ay);
            den += ww[e];
        }
        const float inv = 1.0f / den;                  // den >= 0.1*16
        float2 o;
        o.x = fmaxf(fmaf(ax, inv, bv.x), 0.f);
        o.y = fmaxf(fmaf(ay, inv, bv.y), 0.f);
        ((float2*)(out + (size_t)node * U_DIM + slice * 16))[j] = o;
    }
}

extern "C" void kernel_launch(void* const* d_in, const int* in_sizes, int n_in,
                              void* d_out, int out_size, void* d_ws, size_t ws_size,
                              hipStream_t stream) {
    const float* feat = (const float*)d_in[0];
    // d_in[1] = edge_rows: unused — rows are arange(E)//DEG, node i owns edges [16i,16i+16)
    const int* cols  = (const int*)d_in[2];
    const float* wts = (const float*)d_in[3];
    const float* W   = (const float*)d_in[4];
    const float* b   = (const float*)d_in[5];
    float* out = (float*)d_out;

    unsigned short* wt_bf = (unsigned short*)d_ws;                    // 32 KB
    unsigned short* Ys    = (unsigned short*)((char*)d_ws + 32768);   // 25.6 MB slice-major

    cast_w_kernel<<<16384 / 256, 256, 0, stream>>>(W, wt_bf);

    const int nblocks = (N_NODES + M_TILE - 1) / M_TILE;   // 782
    ymat_kernel<<<nblocks, 256, 0, stream>>>(feat, wt_bf, Ys);

    agg_kernel<<<N_SLICES * nblocks, 256, 0, stream>>>(
        (const unsigned int*)Ys, cols, wts, b, out);
}

// Round 5
// 196.028 us; speedup vs baseline: 1.1209x; 1.1209x over previous
//
#include <hip/hip_runtime.h>

#define N_NODES 100000
#define DEG 16
#define D_DIM 128
#define U_DIM 128

typedef __bf16 bf16x8 __attribute__((ext_vector_type(8)));
typedef float f32x4 __attribute__((ext_vector_type(4)));

__device__ __forceinline__ unsigned short f2bf(float x) {
    // round-to-nearest-even fp32 -> bf16 (inputs finite)
    unsigned int u = __float_as_uint(x);
    u += 0x7fffu + ((u >> 16) & 1u);
    return (unsigned short)(u >> 16);
}
__device__ __forceinline__ unsigned int pack2(float a, float b) {
    return (unsigned int)f2bf(a) | ((unsigned int)f2bf(b) << 16);
}

// Y[n][u] = feat[n,:] @ W[:,u] + b[u], stored bf16 row-major [N][128].
// Block = 128 nodes. Wave wv owns u-range [32wv, 32wv+32) x all 128 nodes.
// MFMA with A = W^T (loop-invariant fragments, built once from fp32 W -> no
// separate cast kernel), B = feat rows (32 B/lane contiguous loads).
// D[m=u][n=node] -> each acc reg = 4 consecutive u of one node -> dwordx2 stores.
__global__ __launch_bounds__(256)
void ymat_kernel(const float* __restrict__ feat,
                 const float* __restrict__ W,
                 const float* __restrict__ bias,
                 unsigned short* __restrict__ Y) {
    const int lane = threadIdx.x & 63;
    const int wv = threadIdx.x >> 6;
    const int quad = lane >> 4;
    const int l15 = lane & 15;
    const int n0 = blockIdx.x * 128;
    const int u_base = wv * 32;

    // A fragments: A[m][k] = W^T[u][k] = W[k][u]; m=l15 -> u, k = kc*32+quad*8+j
    bf16x8 afr[2][4];
    #pragma unroll
    for (int ni = 0; ni < 2; ++ni) {
        const int u = u_base + ni * 16 + l15;
        #pragma unroll
        for (int kc = 0; kc < 4; ++kc) {
            union { unsigned short us[8]; bf16x8 v; } pk;
            #pragma unroll
            for (int j = 0; j < 8; ++j)
                pk.us[j] = f2bf(W[(kc * 32 + quad * 8 + j) * 128 + u]);
            afr[ni][kc] = pk.v;
        }
    }
    // bias for D rows: u = u_base + ni*16 + quad*4 + r
    float4 bv0 = *(const float4*)(bias + u_base + quad * 4);
    float4 bv1 = *(const float4*)(bias + u_base + 16 + quad * 4);

    for (int mi = 0; mi < 8; ++mi) {
        const int node = n0 + mi * 16 + l15;
        const int rowc = node < N_NODES ? node : N_NODES - 1;  // clamp; store guarded
        bf16x8 bfr[4];
        #pragma unroll
        for (int kc = 0; kc < 4; ++kc) {   // B[k][n]: n=l15 -> node, k contiguous in feat row
            const float* ap = feat + (size_t)rowc * D_DIM + kc * 32 + quad * 8;
            const float4 a0 = *(const float4*)ap;
            const float4 a1 = *(const float4*)(ap + 4);
            union { unsigned short us[8]; bf16x8 v; } pk;
            pk.us[0] = f2bf(a0.x); pk.us[1] = f2bf(a0.y);
            pk.us[2] = f2bf(a0.z); pk.us[3] = f2bf(a0.w);
            pk.us[4] = f2bf(a1.x); pk.us[5] = f2bf(a1.y);
            pk.us[6] = f2bf(a1.z); pk.us[7] = f2bf(a1.w);
            bfr[kc] = pk.v;
        }
        f32x4 acc0 = (f32x4){0.f, 0.f, 0.f, 0.f};
        f32x4 acc1 = (f32x4){0.f, 0.f, 0.f, 0.f};
        #pragma unroll
        for (int kc = 0; kc < 4; ++kc) {
            acc0 = __builtin_amdgcn_mfma_f32_16x16x32_bf16(afr[0][kc], bfr[kc], acc0, 0, 0, 0);
            acc1 = __builtin_amdgcn_mfma_f32_16x16x32_bf16(afr[1][kc], bfr[kc], acc1, 0, 0, 0);
        }
        if (node < N_NODES) {
            unsigned int* yp = (unsigned int*)(Y + (size_t)node * U_DIM + u_base + quad * 4);
            uint2 s0, s1;
            s0.x = pack2(acc0[0] + bv0.x, acc0[1] + bv0.y);
            s0.y = pack2(acc0[2] + bv0.z, acc0[3] + bv0.w);
            s1.x = pack2(acc1[0] + bv1.x, acc1[1] + bv1.y);
            s1.y = pack2(acc1[2] + bv1.z, acc1[3] + bv1.w);
            *(uint2*)yp = s0;
            *(uint2*)(yp + 8) = s1;   // +16 ushorts
        }
    }
}

// out[n,:] = relu( (sum_e w_e * Y[col_e,:]) / (sum_e w_e) )   (bias already in Y)
// 16 lanes per node, 16 B/lane dwordx4 gathers: one instr = 4 nodes x full 256 B row.
__global__ __launch_bounds__(256, 4)
void agg_kernel(const unsigned short* __restrict__ Y,
                const int* __restrict__ cols,
                const float* __restrict__ wts,
                float* __restrict__ out) {
    const int node = blockIdx.x * 16 + (threadIdx.x >> 4);   // grid exact: 6250*16 = N
    const int d = threadIdx.x & 15;                          // owns dims [8d, 8d+8)
    const int e0 = node * DEG;

    int cc[DEG];
    float ww[DEG];
    #pragma unroll
    for (int q = 0; q < 4; ++q) {
        const int4 c4 = *(const int4*)(cols + e0 + 4 * q);
        const float4 w4 = *(const float4*)(wts + e0 + 4 * q);
        cc[4 * q + 0] = c4.x; cc[4 * q + 1] = c4.y;
        cc[4 * q + 2] = c4.z; cc[4 * q + 3] = c4.w;
        ww[4 * q + 0] = w4.x; ww[4 * q + 1] = w4.y;
        ww[4 * q + 2] = w4.z; ww[4 * q + 3] = w4.w;
    }
    float den = 0.f;
    #pragma unroll
    for (int e = 0; e < DEG; ++e) den += ww[e];

    float a0 = 0.f, a1 = 0.f, a2 = 0.f, a3 = 0.f;
    float a4 = 0.f, a5 = 0.f, a6 = 0.f, a7 = 0.f;
    #pragma unroll
    for (int h = 0; h < 2; ++h) {           // two 8-deep batches of dwordx4 gathers
        uint4 p[8];
        #pragma unroll
        for (int e = 0; e < 8; ++e)
            p[e] = *(const uint4*)(Y + (size_t)cc[h * 8 + e] * U_DIM + d * 8);
        #pragma unroll
        for (int e = 0; e < 8; ++e) {
            const float w = ww[h * 8 + e];
            a0 = fmaf(w, __uint_as_float(p[e].x << 16), a0);
            a1 = fmaf(w, __uint_as_float(p[e].x & 0xffff0000u), a1);
            a2 = fmaf(w, __uint_as_float(p[e].y << 16), a2);
            a3 = fmaf(w, __uint_as_float(p[e].y & 0xffff0000u), a3);
            a4 = fmaf(w, __uint_as_float(p[e].z << 16), a4);
            a5 = fmaf(w, __uint_as_float(p[e].z & 0xffff0000u), a5);
            a6 = fmaf(w, __uint_as_float(p[e].w << 16), a6);
            a7 = fmaf(w, __uint_as_float(p[e].w & 0xffff0000u), a7);
        }
    }
    const float inv = 1.0f / den;           // den >= 0.1*16
    f32x4 o0, o1;
    o0[0] = fmaxf(a0 * inv, 0.f); o0[1] = fmaxf(a1 * inv, 0.f);
    o0[2] = fmaxf(a2 * inv, 0.f); o0[3] = fmaxf(a3 * inv, 0.f);
    o1[0] = fmaxf(a4 * inv, 0.f); o1[1] = fmaxf(a5 * inv, 0.f);
    o1[2] = fmaxf(a6 * inv, 0.f); o1[3] = fmaxf(a7 * inv, 0.f);
    f32x4* op = (f32x4*)(out + (size_t)node * U_DIM + d * 8);
    __builtin_nontemporal_store(o0, op);        // write-once stream: don't evict Y from L2
    __builtin_nontemporal_store(o1, op + 1);
}

extern "C" void kernel_launch(void* const* d_in, const int* in_sizes, int n_in,
                              void* d_out, int out_size, void* d_ws, size_t ws_size,
                              hipStream_t stream) {
    const float* feat = (const float*)d_in[0];
    // d_in[1] = edge_rows: unused — rows are arange(E)//DEG, node i owns edges [16i,16i+16)
    const int* cols  = (const int*)d_in[2];
    const float* wts = (const float*)d_in[3];
    const float* W   = (const float*)d_in[4];
    const float* b   = (const float*)d_in[5];
    float* out = (float*)d_out;

    unsigned short* Y = (unsigned short*)d_ws;   // 25.6 MB bf16 [N][128]

    const int nblocks = (N_NODES + 127) / 128;   // 782
    ymat_kernel<<<nblocks, 256, 0, stream>>>(feat, W, b, Y);

    agg_kernel<<<N_NODES / 16, 256, 0, stream>>>(Y, cols, wts, out);
}

// Round 6
// 192.034 us; speedup vs baseline: 1.1442x; 1.0208x over previous
//
#include <hip/hip_runtime.h>

#define N_NODES 100000
#define DEG 16
#define D_DIM 128
#define U_DIM 128

typedef __bf16 bf16x8 __attribute__((ext_vector_type(8)));
typedef float f32x4 __attribute__((ext_vector_type(4)));

__device__ __forceinline__ unsigned short f2bf(float x) {
    // round-to-nearest-even fp32 -> bf16 (inputs finite)
    unsigned int u = __float_as_uint(x);
    u += 0x7fffu + ((u >> 16) & 1u);
    return (unsigned short)(u >> 16);
}
__device__ __forceinline__ unsigned int pack2(float a, float b) {
    return (unsigned int)f2bf(a) | ((unsigned int)f2bf(b) << 16);
}

// W fp32 [K=128][U=128] row-major -> WT bf16 [U][K] (A-fragment friendly: k contiguous)
__global__ void cast_w_kernel(const float* __restrict__ W,
                              unsigned short* __restrict__ WT) {
    int t = blockIdx.x * 256 + threadIdx.x;   // t < 16384
    int k = t >> 7, n = t & 127;
    WT[n * 128 + k] = f2bf(W[t]);
}

// Y[n][u] = feat[n,:] @ W[:,u] + b[u], stored bf16 row-major [N][128].
// A = W^T (loop-invariant bf16x8 fragments from WT), B = feat rows (32 B/lane
// contiguous fp32->bf16). D[m=u][n=node]: each acc reg = 4 consecutive u of one
// node -> two 8 B stores per lane per node group.
__global__ __launch_bounds__(256)
void ymat_kernel(const float* __restrict__ feat,
                 const unsigned short* __restrict__ WT,   // bf16 [U][K]
                 const float* __restrict__ bias,
                 unsigned short* __restrict__ Y) {
    const int lane = threadIdx.x & 63;
    const int wv = threadIdx.x >> 6;
    const int quad = lane >> 4;
    const int l15 = lane & 15;
    const int n0 = blockIdx.x * 128;
    const int u_base = wv * 32;

    // A fragments: A[m=l15 -> u][k = kc*32+quad*8+j]
    bf16x8 afr[2][4];
    #pragma unroll
    for (int ni = 0; ni < 2; ++ni) {
        const int u = u_base + ni * 16 + l15;
        #pragma unroll
        for (int kc = 0; kc < 4; ++kc)
            afr[ni][kc] = *(const bf16x8*)(WT + u * 128 + kc * 32 + quad * 8);
    }
    // bias for D rows: u = u_base + ni*16 + quad*4 + r
    float4 bv0 = *(const float4*)(bias + u_base + quad * 4);
    float4 bv1 = *(const float4*)(bias + u_base + 16 + quad * 4);

    for (int mi = 0; mi < 8; ++mi) {
        const int node = n0 + mi * 16 + l15;
        const int rowc = node < N_NODES ? node : N_NODES - 1;  // clamp; store guarded
        bf16x8 bfr[4];
        #pragma unroll
        for (int kc = 0; kc < 4; ++kc) {   // B[k][n]: n=l15 -> node, k contiguous in feat row
            const float* ap = feat + (size_t)rowc * D_DIM + kc * 32 + quad * 8;
            const float4 a0 = *(const float4*)ap;
            const float4 a1 = *(const float4*)(ap + 4);
            union { unsigned short us[8]; bf16x8 v; } pk;
            pk.us[0] = f2bf(a0.x); pk.us[1] = f2bf(a0.y);
            pk.us[2] = f2bf(a0.z); pk.us[3] = f2bf(a0.w);
            pk.us[4] = f2bf(a1.x); pk.us[5] = f2bf(a1.y);
            pk.us[6] = f2bf(a1.z); pk.us[7] = f2bf(a1.w);
            bfr[kc] = pk.v;
        }
        f32x4 acc0 = (f32x4){0.f, 0.f, 0.f, 0.f};
        f32x4 acc1 = (f32x4){0.f, 0.f, 0.f, 0.f};
        #pragma unroll
        for (int kc = 0; kc < 4; ++kc) {
            acc0 = __builtin_amdgcn_mfma_f32_16x16x32_bf16(afr[0][kc], bfr[kc], acc0, 0, 0, 0);
            acc1 = __builtin_amdgcn_mfma_f32_16x16x32_bf16(afr[1][kc], bfr[kc], acc1, 0, 0, 0);
        }
        if (node < N_NODES) {
            unsigned int* yp = (unsigned int*)(Y + (size_t)node * U_DIM + u_base + quad * 4);
            uint2 s0, s1;
            s0.x = pack2(acc0[0] + bv0.x, acc0[1] + bv0.y);
            s0.y = pack2(acc0[2] + bv0.z, acc0[3] + bv0.w);
            s1.x = pack2(acc1[0] + bv1.x, acc1[1] + bv1.y);
            s1.y = pack2(acc1[2] + bv1.z, acc1[3] + bv1.w);
            *(uint2*)yp = s0;
            *(uint2*)(yp + 8) = s1;   // +16 ushorts
        }
    }
}

// out[n, phase*64 : +64] = relu( (sum_e w_e * Y[col_e, half]) / (sum_e w_e) )
// Two u-phases via grid ordering: blocks [0,3125) do dims [0,64), blocks
// [3125,6250) do dims [64,128). In-order-ish dispatch makes each phase's gather
// pool 12.8 MB (vs 25.6) -> higher per-XCD L2 hit rate. 8 lanes/node, uint4
// gathers: one instr = 8 nodes x full 128 B half-row (fully-used 64 B lines).
__global__ __launch_bounds__(256, 4)
void agg_kernel(const unsigned short* __restrict__ Y,
                const int* __restrict__ cols,
                const float* __restrict__ wts,
                float* __restrict__ out) {
    const int phase = (blockIdx.x >= 3125) ? 1 : 0;
    const int nb = blockIdx.x - phase * 3125;
    const int node = nb * 32 + (threadIdx.x >> 3);   // exact: 3125*32 = N_NODES
    const int ubase = phase * 64 + (threadIdx.x & 7) * 8;   // owns 8 dims
    const int e0 = node * DEG;

    int cc[DEG];
    float ww[DEG];
    #pragma unroll
    for (int q = 0; q < 4; ++q) {
        const int4 c4 = *(const int4*)(cols + e0 + 4 * q);
        const float4 w4 = *(const float4*)(wts + e0 + 4 * q);
        cc[4 * q + 0] = c4.x; cc[4 * q + 1] = c4.y;
        cc[4 * q + 2] = c4.z; cc[4 * q + 3] = c4.w;
        ww[4 * q + 0] = w4.x; ww[4 * q + 1] = w4.y;
        ww[4 * q + 2] = w4.z; ww[4 * q + 3] = w4.w;
    }
    float den = 0.f;
    #pragma unroll
    for (int e = 0; e < DEG; ++e) den += ww[e];

    float a0 = 0.f, a1 = 0.f, a2 = 0.f, a3 = 0.f;
    float a4 = 0.f, a5 = 0.f, a6 = 0.f, a7 = 0.f;
    #pragma unroll
    for (int h = 0; h < 2; ++h) {           // two 8-deep batches of uint4 gathers
        uint4 p[8];
        #pragma unroll
        for (int e = 0; e < 8; ++e)
            p[e] = *(const uint4*)(Y + (size_t)cc[h * 8 + e] * U_DIM + ubase);
        #pragma unroll
        for (int e = 0; e < 8; ++e) {
            const float w = ww[h * 8 + e];
            a0 = fmaf(w, __uint_as_float(p[e].x << 16), a0);
            a1 = fmaf(w, __uint_as_float(p[e].x & 0xffff0000u), a1);
            a2 = fmaf(w, __uint_as_float(p[e].y << 16), a2);
            a3 = fmaf(w, __uint_as_float(p[e].y & 0xffff0000u), a3);
            a4 = fmaf(w, __uint_as_float(p[e].z << 16), a4);
            a5 = fmaf(w, __uint_as_float(p[e].z & 0xffff0000u), a5);
            a6 = fmaf(w, __uint_as_float(p[e].w << 16), a6);
            a7 = fmaf(w, __uint_as_float(p[e].w & 0xffff0000u), a7);
        }
    }
    const float inv = 1.0f / den;           // den >= 0.1*16
    f32x4 o0, o1;
    o0[0] = fmaxf(a0 * inv, 0.f); o0[1] = fmaxf(a1 * inv, 0.f);
    o0[2] = fmaxf(a2 * inv, 0.f); o0[3] = fmaxf(a3 * inv, 0.f);
    o1[0] = fmaxf(a4 * inv, 0.f); o1[1] = fmaxf(a5 * inv, 0.f);
    o1[2] = fmaxf(a6 * inv, 0.f); o1[3] = fmaxf(a7 * inv, 0.f);
    f32x4* op = (f32x4*)(out + (size_t)node * U_DIM + ubase);
    __builtin_nontemporal_store(o0, op);    // write-once stream: don't evict Y from L2
    __builtin_nontemporal_store(o1, op + 1);
}

extern "C" void kernel_launch(void* const* d_in, const int* in_sizes, int n_in,
                              void* d_out, int out_size, void* d_ws, size_t ws_size,
                              hipStream_t stream) {
    const float* feat = (const float*)d_in[0];
    // d_in[1] = edge_rows: unused — rows are arange(E)//DEG, node i owns edges [16i,16i+16)
    const int* cols  = (const int*)d_in[2];
    const float* wts = (const float*)d_in[3];
    const float* W   = (const float*)d_in[4];
    const float* b   = (const float*)d_in[5];
    float* out = (float*)d_out;

    unsigned short* wt_bf = (unsigned short*)d_ws;                    // 32 KB bf16 [U][K]
    unsigned short* Y     = (unsigned short*)((char*)d_ws + 32768);   // 25.6 MB bf16 [N][128]

    cast_w_kernel<<<16384 / 256, 256, 0, stream>>>(W, wt_bf);

    const int nblocks = (N_NODES + 127) / 128;   // 782
    ymat_kernel<<<nblocks, 256, 0, stream>>>(feat, wt_bf, b, Y);

    agg_kernel<<<6250, 256, 0, stream>>>(Y, cols, wts, out);
}

// Round 7
// 178.656 us; speedup vs baseline: 1.2299x; 1.0749x over previous
//
#include <hip/hip_runtime.h>

#define N_NODES 100000
#define DEG 16
#define D_DIM 128
#define U_DIM 128
#define FSTRIDE 136   // bf16 LDS row stride: 272 B -> 68 dwords -> conflicts <= 2-way

typedef __bf16 bf16x8 __attribute__((ext_vector_type(8)));
typedef float f32x4 __attribute__((ext_vector_type(4)));
typedef int i32x4 __attribute__((ext_vector_type(4)));

__device__ __forceinline__ unsigned short f2bf(float x) {
    // round-to-nearest-even fp32 -> bf16 (inputs finite)
    unsigned int u = __float_as_uint(x);
    u += 0x7fffu + ((u >> 16) & 1u);
    return (unsigned short)(u >> 16);
}
__device__ __forceinline__ unsigned int pack2(float a, float b) {
    return (unsigned int)f2bf(a) | ((unsigned int)f2bf(b) << 16);
}

// W fp32 [K=128][U=128] row-major -> WT bf16 [U][K] (A-fragment friendly: k contiguous)
__global__ void cast_w_kernel(const float* __restrict__ W,
                              unsigned short* __restrict__ WT) {
    int t = blockIdx.x * 256 + threadIdx.x;   // t < 16384
    int k = t >> 7, n = t & 127;
    WT[n * 128 + k] = f2bf(W[t]);
}

// Y[n][u] = feat[n,:] @ W[:,u] + b[u], stored bf16 row-major [N][128].
// feat tile (128 nodes) staged ONCE per block into LDS as bf16 (fixes the R5/R6
// 4x feat re-read: every wave consumed all 128 rows from global). A = W^T
// loop-invariant fragments; B from LDS ds_read_b128. D[m=u][n=node] -> uint2 stores.
__global__ __launch_bounds__(256)
void ymat_kernel(const float* __restrict__ feat,
                 const unsigned short* __restrict__ WT,   // bf16 [U][K]
                 const float* __restrict__ bias,
                 unsigned short* __restrict__ Y) {
    __shared__ __align__(16) unsigned short ftile[128 * FSTRIDE];
    const int lane = threadIdx.x & 63;
    const int wv = threadIdx.x >> 6;
    const int quad = lane >> 4;
    const int l15 = lane & 15;
    const int n0 = blockIdx.x * 128;
    const int u_base = wv * 32;

    // ---- stage: 16384 floats, thread t handles float4 indices j*256+t (1 KB/instr/wave)
    {
        const int t = threadIdx.x;
        #pragma unroll
        for (int j = 0; j < 16; ++j) {
            const int i = j * 256 + t;          // float4 index in tile
            const int row = i >> 5;             // 4i >> 7
            const int col = (i & 31) * 4;
            const int rowc = (n0 + row < N_NODES) ? (n0 + row) : (N_NODES - 1);
            const float4 v = *(const float4*)(feat + (size_t)rowc * D_DIM + col);
            ushort4 s;
            s.x = f2bf(v.x); s.y = f2bf(v.y); s.z = f2bf(v.z); s.w = f2bf(v.w);
            *(ushort4*)&ftile[row * FSTRIDE + col] = s;
        }
    }

    // A fragments: A[m=l15 -> u][k = kc*32+quad*8+j]
    bf16x8 afr[2][4];
    #pragma unroll
    for (int ni = 0; ni < 2; ++ni) {
        const int u = u_base + ni * 16 + l15;
        #pragma unroll
        for (int kc = 0; kc < 4; ++kc)
            afr[ni][kc] = *(const bf16x8*)(WT + u * 128 + kc * 32 + quad * 8);
    }
    // bias for D rows: u = u_base + ni*16 + quad*4 + r
    const float4 bv0 = *(const float4*)(bias + u_base + quad * 4);
    const float4 bv1 = *(const float4*)(bias + u_base + 16 + quad * 4);

    __syncthreads();

    #pragma unroll
    for (int mi = 0; mi < 8; ++mi) {
        const int node = n0 + mi * 16 + l15;
        bf16x8 bfr[4];
        #pragma unroll
        for (int kc = 0; kc < 4; ++kc)   // B[k][n]: n=l15 -> node row in LDS
            bfr[kc] = *(const bf16x8*)&ftile[(mi * 16 + l15) * FSTRIDE + kc * 32 + quad * 8];
        f32x4 acc0 = (f32x4){0.f, 0.f, 0.f, 0.f};
        f32x4 acc1 = (f32x4){0.f, 0.f, 0.f, 0.f};
        #pragma unroll
        for (int kc = 0; kc < 4; ++kc) {
            acc0 = __builtin_amdgcn_mfma_f32_16x16x32_bf16(afr[0][kc], bfr[kc], acc0, 0, 0, 0);
            acc1 = __builtin_amdgcn_mfma_f32_16x16x32_bf16(afr[1][kc], bfr[kc], acc1, 0, 0, 0);
        }
        if (node < N_NODES) {
            unsigned int* yp = (unsigned int*)(Y + (size_t)node * U_DIM + u_base + quad * 4);
            uint2 s0, s1;
            s0.x = pack2(acc0[0] + bv0.x, acc0[1] + bv0.y);
            s0.y = pack2(acc0[2] + bv0.z, acc0[3] + bv0.w);
            s1.x = pack2(acc1[0] + bv1.x, acc1[1] + bv1.y);
            s1.y = pack2(acc1[2] + bv1.z, acc1[3] + bv1.w);
            *(uint2*)yp = s0;
            *(uint2*)(yp + 8) = s1;   // +16 ushorts
        }
    }
}

// out[n, phase*64 : +64] = relu( (sum_e w_e * Y[col_e, half]) / (sum_e w_e) )
// Two u-phases via grid ordering (12.8 MB pool/phase). 8 lanes/node, uint4
// gathers: one instr = 8 nodes x full 128 B half-row. Edge loads nontemporal:
// streamed twice, must not evict the Y working set from L2.
__global__ __launch_bounds__(256, 4)
void agg_kernel(const unsigned short* __restrict__ Y,
                const int* __restrict__ cols,
                const float* __restrict__ wts,
                float* __restrict__ out) {
    const int phase = (blockIdx.x >= 3125) ? 1 : 0;
    const int nb = blockIdx.x - phase * 3125;
    const int node = nb * 32 + (threadIdx.x >> 3);   // exact: 3125*32 = N_NODES
    const int ubase = phase * 64 + (threadIdx.x & 7) * 8;   // owns 8 dims
    const int e0 = node * DEG;

    int cc[DEG];
    float ww[DEG];
    #pragma unroll
    for (int q = 0; q < 4; ++q) {
        const i32x4 c4 = __builtin_nontemporal_load((const i32x4*)(cols + e0 + 4 * q));
        const f32x4 w4 = __builtin_nontemporal_load((const f32x4*)(wts + e0 + 4 * q));
        cc[4 * q + 0] = c4[0]; cc[4 * q + 1] = c4[1];
        cc[4 * q + 2] = c4[2]; cc[4 * q + 3] = c4[3];
        ww[4 * q + 0] = w4[0]; ww[4 * q + 1] = w4[1];
        ww[4 * q + 2] = w4[2]; ww[4 * q + 3] = w4[3];
    }
    float den = 0.f;
    #pragma unroll
    for (int e = 0; e < DEG; ++e) den += ww[e];

    float a0 = 0.f, a1 = 0.f, a2 = 0.f, a3 = 0.f;
    float a4 = 0.f, a5 = 0.f, a6 = 0.f, a7 = 0.f;
    #pragma unroll
    for (int h = 0; h < 2; ++h) {           // two 8-deep batches of uint4 gathers
        uint4 p[8];
        #pragma unroll
        for (int e = 0; e < 8; ++e)
            p[e] = *(const uint4*)(Y + (size_t)cc[h * 8 + e] * U_DIM + ubase);
        #pragma unroll
        for (int e = 0; e < 8; ++e) {
            const float w = ww[h * 8 + e];
            a0 = fmaf(w, __uint_as_float(p[e].x << 16), a0);
            a1 = fmaf(w, __uint_as_float(p[e].x & 0xffff0000u), a1);
            a2 = fmaf(w, __uint_as_float(p[e].y << 16), a2);
            a3 = fmaf(w, __uint_as_float(p[e].y & 0xffff0000u), a3);
            a4 = fmaf(w, __uint_as_float(p[e].z << 16), a4);
            a5 = fmaf(w, __uint_as_float(p[e].z & 0xffff0000u), a5);
            a6 = fmaf(w, __uint_as_float(p[e].w << 16), a6);
            a7 = fmaf(w, __uint_as_float(p[e].w & 0xffff0000u), a7);
        }
    }
    const float inv = 1.0f / den;           // den >= 0.1*16
    f32x4 o0, o1;
    o0[0] = fmaxf(a0 * inv, 0.f); o0[1] = fmaxf(a1 * inv, 0.f);
    o0[2] = fmaxf(a2 * inv, 0.f); o0[3] = fmaxf(a3 * inv, 0.f);
    o1[0] = fmaxf(a4 * inv, 0.f); o1[1] = fmaxf(a5 * inv, 0.f);
    o1[2] = fmaxf(a6 * inv, 0.f); o1[3] = fmaxf(a7 * inv, 0.f);
    f32x4* op = (f32x4*)(out + (size_t)node * U_DIM + ubase);
    __builtin_nontemporal_store(o0, op);    // write-once stream
    __builtin_nontemporal_store(o1, op + 1);
}

extern "C" void kernel_launch(void* const* d_in, const int* in_sizes, int n_in,
                              void* d_out, int out_size, void* d_ws, size_t ws_size,
                              hipStream_t stream) {
    const float* feat = (const float*)d_in[0];
    // d_in[1] = edge_rows: unused — rows are arange(E)//DEG, node i owns edges [16i,16i+16)
    const int* cols  = (const int*)d_in[2];
    const float* wts = (const float*)d_in[3];
    const float* W   = (const float*)d_in[4];
    const float* b   = (const float*)d_in[5];
    float* out = (float*)d_out;

    unsigned short* wt_bf = (unsigned short*)d_ws;                    // 32 KB bf16 [U][K]
    unsigned short* Y     = (unsigned short*)((char*)d_ws + 32768);   // 25.6 MB bf16 [N][128]

    cast_w_kernel<<<16384 / 256, 256, 0, stream>>>(W, wt_bf);

    const int nblocks = (N_NODES + 127) / 128;   // 782
    ymat_kernel<<<nblocks, 256, 0, stream>>>(feat, wt_bf, b, Y);

    agg_kernel<<<6250, 256, 0, stream>>>(Y, cols, wts, out);
}

// Round 8
// 176.682 us; speedup vs baseline: 1.2436x; 1.0112x over previous
//
#include <hip/hip_runtime.h>

#define N_NODES 100000
#define DEG 16
#define D_DIM 128
#define U_DIM 128
#define FSTRIDE 136   // bf16 LDS row stride: 272 B -> 68 dwords -> conflicts <= 2-way

typedef __bf16 bf16x8 __attribute__((ext_vector_type(8)));
typedef float f32x4 __attribute__((ext_vector_type(4)));

__device__ __forceinline__ unsigned short f2bf(float x) {
    // round-to-nearest-even fp32 -> bf16 (inputs finite)
    unsigned int u = __float_as_uint(x);
    u += 0x7fffu + ((u >> 16) & 1u);
    return (unsigned short)(u >> 16);
}
__device__ __forceinline__ unsigned int pack2(float a, float b) {
    return (unsigned int)f2bf(a) | ((unsigned int)f2bf(b) << 16);
}

// W fp32 [K=128][U=128] row-major -> WT bf16 [U][K] (A-fragment friendly: k contiguous)
__global__ void cast_w_kernel(const float* __restrict__ W,
                              unsigned short* __restrict__ WT) {
    int t = blockIdx.x * 256 + threadIdx.x;   // t < 16384
    int k = t >> 7, n = t & 127;
    WT[n * 128 + k] = f2bf(W[t]);
}

// Y[n][u] = feat[n,:] @ W[:,u] + b[u], stored bf16 row-major [N][128].
// feat tile (128 nodes) staged ONCE per block into LDS as bf16. A = W^T
// loop-invariant fragments; B from LDS ds_read_b128. D[m=u][n=node] -> uint2 stores.
__global__ __launch_bounds__(256)
void ymat_kernel(const float* __restrict__ feat,
                 const unsigned short* __restrict__ WT,   // bf16 [U][K]
                 const float* __restrict__ bias,
                 unsigned short* __restrict__ Y) {
    __shared__ __align__(16) unsigned short ftile[128 * FSTRIDE];
    const int lane = threadIdx.x & 63;
    const int wv = threadIdx.x >> 6;
    const int quad = lane >> 4;
    const int l15 = lane & 15;
    const int n0 = blockIdx.x * 128;
    const int u_base = wv * 32;

    // ---- stage: 16384 floats, thread t handles float4 indices j*256+t (1 KB/instr/wave)
    {
        const int t = threadIdx.x;
        #pragma unroll
        for (int j = 0; j < 16; ++j) {
            const int i = j * 256 + t;          // float4 index in tile
            const int row = i >> 5;
            const int col = (i & 31) * 4;
            const int rowc = (n0 + row < N_NODES) ? (n0 + row) : (N_NODES - 1);
            const float4 v = *(const float4*)(feat + (size_t)rowc * D_DIM + col);
            ushort4 s;
            s.x = f2bf(v.x); s.y = f2bf(v.y); s.z = f2bf(v.z); s.w = f2bf(v.w);
            *(ushort4*)&ftile[row * FSTRIDE + col] = s;
        }
    }

    // A fragments: A[m=l15 -> u][k = kc*32+quad*8+j]
    bf16x8 afr[2][4];
    #pragma unroll
    for (int ni = 0; ni < 2; ++ni) {
        const int u = u_base + ni * 16 + l15;
        #pragma unroll
        for (int kc = 0; kc < 4; ++kc)
            afr[ni][kc] = *(const bf16x8*)(WT + u * 128 + kc * 32 + quad * 8);
    }
    // bias for D rows: u = u_base + ni*16 + quad*4 + r
    const float4 bv0 = *(const float4*)(bias + u_base + quad * 4);
    const float4 bv1 = *(const float4*)(bias + u_base + 16 + quad * 4);

    __syncthreads();

    #pragma unroll
    for (int mi = 0; mi < 8; ++mi) {
        const int node = n0 + mi * 16 + l15;
        bf16x8 bfr[4];
        #pragma unroll
        for (int kc = 0; kc < 4; ++kc)   // B[k][n]: n=l15 -> node row in LDS
            bfr[kc] = *(const bf16x8*)&ftile[(mi * 16 + l15) * FSTRIDE + kc * 32 + quad * 8];
        f32x4 acc0 = (f32x4){0.f, 0.f, 0.f, 0.f};
        f32x4 acc1 = (f32x4){0.f, 0.f, 0.f, 0.f};
        #pragma unroll
        for (int kc = 0; kc < 4; ++kc) {
            acc0 = __builtin_amdgcn_mfma_f32_16x16x32_bf16(afr[0][kc], bfr[kc], acc0, 0, 0, 0);
            acc1 = __builtin_amdgcn_mfma_f32_16x16x32_bf16(afr[1][kc], bfr[kc], acc1, 0, 0, 0);
        }
        if (node < N_NODES) {
            unsigned int* yp = (unsigned int*)(Y + (size_t)node * U_DIM + u_base + quad * 4);
            uint2 s0, s1;
            s0.x = pack2(acc0[0] + bv0.x, acc0[1] + bv0.y);
            s0.y = pack2(acc0[2] + bv0.z, acc0[3] + bv0.w);
            s1.x = pack2(acc1[0] + bv1.x, acc1[1] + bv1.y);
            s1.y = pack2(acc1[2] + bv1.z, acc1[3] + bv1.w);
            *(uint2*)yp = s0;
            *(uint2*)(yp + 8) = s1;   // +16 ushorts
        }
    }
}

// out[n, phase*64 : +64] = relu( (sum_e w_e * Y[col_e, half]) / (sum_e w_e) )
// Two u-phases via grid ordering (12.8 MB pool/phase). 8 lanes/node, uint4
// gathers: one instr = 8 nodes x full 128 B half-row (aligned, fully-used lines).
// Edge loads PLAIN cached (R7 showed nt loads refetch +9 MB in phase 1: +2.4 us).
__global__ __launch_bounds__(256, 4)
void agg_kernel(const unsigned short* __restrict__ Y,
                const int* __restrict__ cols,
                const float* __restrict__ wts,
                float* __restrict__ out) {
    const int phase = (blockIdx.x >= 3125) ? 1 : 0;
    const int nb = blockIdx.x - phase * 3125;
    const int node = nb * 32 + (threadIdx.x >> 3);   // exact: 3125*32 = N_NODES
    const int ubase = phase * 64 + (threadIdx.x & 7) * 8;   // owns 8 dims
    const int e0 = node * DEG;

    int cc[DEG];
    float ww[DEG];
    #pragma unroll
    for (int q = 0; q < 4; ++q) {
        const int4 c4 = *(const int4*)(cols + e0 + 4 * q);
        const float4 w4 = *(const float4*)(wts + e0 + 4 * q);
        cc[4 * q + 0] = c4.x; cc[4 * q + 1] = c4.y;
        cc[4 * q + 2] = c4.z; cc[4 * q + 3] = c4.w;
        ww[4 * q + 0] = w4.x; ww[4 * q + 1] = w4.y;
        ww[4 * q + 2] = w4.z; ww[4 * q + 3] = w4.w;
    }
    float den = 0.f;
    #pragma unroll
    for (int e = 0; e < DEG; ++e) den += ww[e];

    float a0 = 0.f, a1 = 0.f, a2 = 0.f, a3 = 0.f;
    float a4 = 0.f, a5 = 0.f, a6 = 0.f, a7 = 0.f;
    #pragma unroll
    for (int h = 0; h < 2; ++h) {           // two 8-deep batches of uint4 gathers
        uint4 p[8];
        #pragma unroll
        for (int e = 0; e < 8; ++e)
            p[e] = *(const uint4*)(Y + (size_t)cc[h * 8 + e] * U_DIM + ubase);
        #pragma unroll
        for (int e = 0; e < 8; ++e) {
            const float w = ww[h * 8 + e];
            a0 = fmaf(w, __uint_as_float(p[e].x << 16), a0);
            a1 = fmaf(w, __uint_as_float(p[e].x & 0xffff0000u), a1);
            a2 = fmaf(w, __uint_as_float(p[e].y << 16), a2);
            a3 = fmaf(w, __uint_as_float(p[e].y & 0xffff0000u), a3);
            a4 = fmaf(w, __uint_as_float(p[e].z << 16), a4);
            a5 = fmaf(w, __uint_as_float(p[e].z & 0xffff0000u), a5);
            a6 = fmaf(w, __uint_as_float(p[e].w << 16), a6);
            a7 = fmaf(w, __uint_as_float(p[e].w & 0xffff0000u), a7);
        }
    }
    const float inv = 1.0f / den;           // den >= 0.1*16
    f32x4 o0, o1;
    o0[0] = fmaxf(a0 * inv, 0.f); o0[1] = fmaxf(a1 * inv, 0.f);
    o0[2] = fmaxf(a2 * inv, 0.f); o0[3] = fmaxf(a3 * inv, 0.f);
    o1[0] = fmaxf(a4 * inv, 0.f); o1[1] = fmaxf(a5 * inv, 0.f);
    o1[2] = fmaxf(a6 * inv, 0.f); o1[3] = fmaxf(a7 * inv, 0.f);
    f32x4* op = (f32x4*)(out + (size_t)node * U_DIM + ubase);
    __builtin_nontemporal_store(o0, op);    // write-once stream: don't evict Y from L2
    __builtin_nontemporal_store(o1, op + 1);
}

extern "C" void kernel_launch(void* const* d_in, const int* in_sizes, int n_in,
                              void* d_out, int out_size, void* d_ws, size_t ws_size,
                              hipStream_t stream) {
    const float* feat = (const float*)d_in[0];
    // d_in[1] = edge_rows: unused — rows are arange(E)//DEG, node i owns edges [16i,16i+16)
    const int* cols  = (const int*)d_in[2];
    const float* wts = (const float*)d_in[3];
    const float* W   = (const float*)d_in[4];
    const float* b   = (const float*)d_in[5];
    float* out = (float*)d_out;

    unsigned short* wt_bf = (unsigned short*)d_ws;                    // 32 KB bf16 [U][K]
    unsigned short* Y     = (unsigned short*)((char*)d_ws + 32768);   // 25.6 MB bf16 [N][128]

    cast_w_kernel<<<16384 / 256, 256, 0, stream>>>(W, wt_bf);

    const int nblocks = (N_NODES + 127) / 128;   // 782
    ymat_kernel<<<nblocks, 256, 0, stream>>>(feat, wt_bf, b, Y);

    agg_kernel<<<6250, 256, 0, stream>>>(Y, cols, wts, out);
}